// Round 7
// baseline (237.979 us; speedup 1.0000x reference)
//
#include <hip/hip_runtime.h>
#include <cstdint>

// ---------------- problem constants ----------------
#define BB 8
#define SS 2048
#define DD 1024
#define HH 16
#define HDIM 64
#define MTOT (BB*SS)          // 16384
#define NQKV 3072

typedef __attribute__((ext_vector_type(8))) __bf16 bf16x8;
typedef __attribute__((ext_vector_type(4))) float f32x4;

#define AS1(p) ((const __attribute__((address_space(1))) void*)(p))
#define AS3(p) ((__attribute__((address_space(3))) void*)(p))

__device__ __forceinline__ float bf2f(uint16_t u){
  return __uint_as_float(((uint32_t)u) << 16);
}
__device__ __forceinline__ uint16_t f2bf(float f){
  uint32_t u = __float_as_uint(f);
  return (uint16_t)((u + 0x7fffu + ((u >> 16) & 1u)) >> 16);
}

// ---------------- merged prep kernel ----------------
__global__ __launch_bounds__(256)
void k_prep(const float* __restrict__ x,
            const float* __restrict__ Wq, const float* __restrict__ Wk,
            const float* __restrict__ Wv, const float* __restrict__ Wo,
            const float* __restrict__ bq, const float* __restrict__ bk,
            const float* __restrict__ bv,
            uint16_t* __restrict__ xb, uint16_t* __restrict__ Wt,
            uint16_t* __restrict__ WoT, float* __restrict__ bqkv)
{
  __shared__ float t[32][33];
  const int blk = blockIdx.x, tid = threadIdx.x;
  if (blk < 2048){
    const int n4 = MTOT*DD/4;
    for (int i = blk*256 + tid; i < n4; i += 2048*256){
      float4 v = reinterpret_cast<const float4*>(x)[i];
      ushort4 o;
      o.x = f2bf(v.x); o.y = f2bf(v.y); o.z = f2bf(v.z); o.w = f2bf(v.w);
      reinterpret_cast<ushort4*>(xb)[i] = o;
    }
  } else if (blk < 6144){
    const int zb = blk - 2048;
    const int z = zb >> 10, rem = zb & 1023;
    const int by = rem >> 5, bx = rem & 31;
    const float* src = (z==0)?Wq:(z==1)?Wk:(z==2)?Wv:Wo;
    uint16_t* dst = (z<3) ? (Wt + (size_t)z*1024*1024) : WoT;
    const int k0 = by*32, n0 = bx*32;
    const int tx = tid & 31, ty = tid >> 5;
    #pragma unroll
    for (int r = 0; r < 4; ++r)
      t[ty + r*8][tx] = src[(size_t)(k0 + ty + r*8)*1024 + n0 + tx];
    __syncthreads();
    #pragma unroll
    for (int r = 0; r < 4; ++r)
      dst[(size_t)(n0 + ty + r*8)*1024 + k0 + tx] = f2bf(t[tx][ty + r*8]);
  } else {
    const int i = (blk - 6144)*256 + tid;
    if (i < NQKV)
      bqkv[i] = (i < 1024) ? bq[i] : (i < 2048) ? bk[i-1024] : bv[i-2048];
  }
}

// ============ 256x256 8-phase GEMM (R6 schedule, unchanged) ============
#define BARRIER __builtin_amdgcn_s_barrier()

#define READA(BUF, MH) { \
  const uint16_t* _sl = lds + ((BUF)*4 + (MH))*8192; \
  _Pragma("unroll") \
  for (int f = 0; f < 4; ++f) \
    _Pragma("unroll") \
    for (int ks = 0; ks < 2; ++ks) \
      a[f][ks] = *(const bf16x8*)(_sl + (wm*64 + f*16 + l15)*64 + (((ks*4 + l4) ^ l7)<<3)); \
}

#define READB(BUF, NH, BV) { \
  const uint16_t* _sl = lds + ((BUF)*4 + 2 + (NH))*8192; \
  _Pragma("unroll") \
  for (int j = 0; j < 2; ++j) \
    _Pragma("unroll") \
    for (int ks = 0; ks < 2; ++ks) \
      BV[j][ks] = *(const bf16x8*)(_sl + (wn*32 + j*16 + l15)*64 + (((ks*4 + l4) ^ l7)<<3)); \
}

#define MMA(MH, NH, BV) { \
  __builtin_amdgcn_s_setprio(1); \
  _Pragma("unroll") \
  for (int ks = 0; ks < 2; ++ks) \
    _Pragma("unroll") \
    for (int f = 0; f < 4; ++f) \
      _Pragma("unroll") \
      for (int j = 0; j < 2; ++j) \
        acc[(MH)*4+f][(NH)*2+j] = __builtin_amdgcn_mfma_f32_16x16x32_bf16(a[f][ks], BV[j][ks], acc[(MH)*4+f][(NH)*2+j], 0, 0, 0); \
  __builtin_amdgcn_s_setprio(0); }

#define STAGEA(T, H) { \
  char* _d = (char*)lds + ((((T)&1)*4 + (H))*16384) + wave*1024; \
  _Pragma("unroll") \
  for (int l = 0; l < 2; ++l) \
    __builtin_amdgcn_global_load_lds(AS1(pA + (l*131072 + (H)*65536 + (T)*64)), AS3(_d + l*8192), 16, 0, 0); \
}

#define STAGEB(T, H) { \
  char* _d = (char*)lds + ((((T)&1)*4 + 2 + (H))*16384) + wave*1024; \
  _Pragma("unroll") \
  for (int l = 0; l < 2; ++l) \
    __builtin_amdgcn_global_load_lds(AS1(pB + (l*131072 + (H)*32768 + (T)*64)), AS3(_d + l*8192), 16, 0, 0); \
}

template<int EPI, int NB_T>
__global__ __launch_bounds__(512)
void k_gemm256(const uint16_t* __restrict__ A, const uint16_t* __restrict__ Bt,
               const float* __restrict__ bias, const uint16_t* __restrict__ resid16,
               uint16_t* __restrict__ Cout)
{
  constexpr int N = NB_T * 256;
  __shared__ uint16_t lds[8 * 8192];   // 128 KiB
  const int tid = threadIdx.x;
  const int lane = tid & 63, wave = tid >> 6;
  const int wm = wave >> 2, wn = wave & 3;     // 2 M-waves x 4 N-waves
  const int l15 = lane & 15, l4 = lane >> 4, l7 = lane & 7;

  const int nwg = gridDim.x, cpx = nwg >> 3, bid = blockIdx.x;
  const int wg = (bid & 7) * cpx + (bid >> 3);
  const int m0 = (wg / NB_T) << 8, n0 = (wg % NB_T) << 8;

  const int colbase = (((tid & 7) ^ ((tid >> 3) & 7)) << 3);
  const uint16_t* pA = A  + (size_t)(m0 + (tid >> 3)) * 1024 + colbase;
  const uint16_t* pB = Bt + (size_t)(n0 + ((tid >> 8) << 6) + ((tid >> 3) & 31)) * 1024 + colbase;

  f32x4 acc[8][4] = {};
  bf16x8 a[4][2], b0[2][2], b1[2][2];

  STAGEA(0,0); STAGEB(0,1); STAGEA(0,1); STAGEB(0,0);
  STAGEA(1,0); STAGEB(1,1); STAGEA(1,1);
  asm volatile("s_waitcnt vmcnt(6)" ::: "memory");
  BARRIER;

  #pragma unroll
  for (int I = 0; I < 7; ++I){
    const int e = 2*I;
    READA(0,0); READB(0,0,b0); STAGEB(e+1, 0);
    BARRIER; MMA(0,0,b0); BARRIER;
    READB(0,1,b1); STAGEA(e+2, 0);
    BARRIER; MMA(0,1,b1); BARRIER;
    READA(0,1); STAGEB(e+2, 1);
    BARRIER; MMA(1,1,b1); BARRIER;
    STAGEA(e+2, 1);
    asm volatile("s_waitcnt vmcnt(6)" ::: "memory");
    BARRIER; MMA(1,0,b0); BARRIER;
    READA(1,0); READB(1,0,b0); STAGEB(e+2, 0);
    BARRIER; MMA(0,0,b0); BARRIER;
    READB(1,1,b1); STAGEA(e+3, 0);
    BARRIER; MMA(0,1,b1); BARRIER;
    READA(1,1); STAGEB(e+3, 1);
    BARRIER; MMA(1,1,b1); BARRIER;
    STAGEA(e+3, 1);
    asm volatile("s_waitcnt vmcnt(6)" ::: "memory");
    BARRIER; MMA(1,0,b0); BARRIER;
  }

  {
    READA(0,0); READB(0,0,b0); STAGEB(15, 0);
    BARRIER; MMA(0,0,b0); BARRIER;
    READB(0,1,b1);
    BARRIER; MMA(0,1,b1); BARRIER;
    READA(0,1);
    BARRIER; MMA(1,1,b1); BARRIER;
    asm volatile("s_waitcnt vmcnt(0)" ::: "memory");
    BARRIER; MMA(1,0,b0); BARRIER;
    READA(1,0); READB(1,0,b0);
    BARRIER; MMA(0,0,b0); BARRIER;
    READB(1,1,b1);
    BARRIER; MMA(0,1,b1); BARRIER;
    READA(1,1);
    BARRIER; MMA(1,1,b1); BARRIER;
    MMA(1,0,b0);
  }

  #pragma unroll
  for (int mh = 0; mh < 2; ++mh)
  #pragma unroll
  for (int f = 0; f < 4; ++f)
  #pragma unroll
  for (int nh = 0; nh < 2; ++nh)
  #pragma unroll
  for (int j = 0; j < 2; ++j){
    const int gcol = n0 + wn*64 + nh*32 + j*16 + l15;
    const float bi = bias[gcol];
    const int rbase = m0 + wm*128 + mh*64 + f*16 + l4*4;
    #pragma unroll
    for (int rr = 0; rr < 4; ++rr){
      const size_t idx = (size_t)(rbase + rr)*N + gcol;
      float v = acc[mh*4+f][nh*2+j][rr] + bi;
      if (EPI == 1) v += bf2f(resid16[idx]);
      Cout[idx] = f2bf(v);
    }
  }
}

// ================= parallel pooling path =================
// Shift-free softmax is exact here: |scores| <~ 2 by construction (0.02-scaled
// weights), exp() in fp32 is safe without max subtraction, so the per-(b,h)
// pooling is two embarrassingly-parallel weighted-column-sum passes.
//
// k_pool<PASS>: grid 2048 x 256 thr. Block handles 8 rows of q (PASS 0) or k
// (PASS 1). Thread owns 4 columns; 16-lane shuffle reduce gives the per-head
// score; E = exp((s+bias)/8 + mask); register-accumulate E*v per column and E
// per head; write per-block partials (unique writers, no LDS in the loop).
template<int PASS>
__global__ __launch_bounds__(256)
void k_pool(const uint16_t* __restrict__ qkv, const float* __restrict__ mask,
            const float* __restrict__ w64, const float* __restrict__ biasp,
            const float* __restrict__ wvecB,
            float* __restrict__ cpart, float* __restrict__ dpart)
{
  __shared__ float probe[1024];
  const int blk = blockIdx.x, tid = threadIdx.x, lane = tid & 63;
  const int r0 = blk*8, b = r0 >> 11;
  #pragma unroll
  for (int k2 = 0; k2 < 4; ++k2){
    const int c = k2*256 + tid;
    probe[c] = (PASS == 0) ? w64[c & 63] : wvecB[b*1024 + c];
  }
  __syncthreads();
  const float bias = biasp[0];
  const uint16_t* base = qkv + (PASS == 0 ? 0 : 1024);
  const int c0 = tid*4;
  const float p0 = probe[c0], p1 = probe[c0+1], p2 = probe[c0+2], p3 = probe[c0+3];
  float r0a = 0.f, r1a = 0.f, r2a = 0.f, r3a = 0.f, dsum = 0.f;
  #pragma unroll
  for (int r = 0; r < 8; ++r){
    const int row = r0 + r;
    const ushort4 raw = *(const ushort4*)(base + (size_t)row*NQKV + c0);
    const float v0 = bf2f(raw.x), v1 = bf2f(raw.y), v2 = bf2f(raw.z), v3 = bf2f(raw.w);
    float s = v0*p0 + v1*p1 + v2*p2 + v3*p3;
    s += __shfl_xor(s, 1); s += __shfl_xor(s, 2);
    s += __shfl_xor(s, 4); s += __shfl_xor(s, 8);
    const float E = __expf((s + bias)*0.125f + mask[row]);
    r0a += v0*E; r1a += v1*E; r2a += v2*E; r3a += v3*E;
    dsum += E;
  }
  float* cp = cpart + (size_t)blk*1024 + c0;
  cp[0] = r0a; cp[1] = r1a; cp[2] = r2a; cp[3] = r3a;
  if ((lane & 15) == 0) dpart[blk*16 + (tid >> 4)] = dsum;
}

// mergeA: grid 256 (b x 32-col chunk), 256 thr -> qav[b][1024], wvec[b][1024]
__global__ __launch_bounds__(256)
void k_mergeA(const float* __restrict__ cpart, const float* __restrict__ dpart,
              const float* __restrict__ wb,
              float* __restrict__ qavB, float* __restrict__ wvecB)
{
  __shared__ float red[8][32];
  __shared__ float dred[256];
  const int blk = blockIdx.x, tid = threadIdx.x;
  const int b = blk >> 5, ch = blk & 31;
  const int c = ch*32 + (tid & 31), pg = tid >> 5;   // 8 groups x 32 partials
  const int h = ch >> 1;
  float s = 0.f;
  #pragma unroll
  for (int p = 0; p < 32; ++p)
    s += cpart[(size_t)(b*256 + pg*32 + p)*1024 + c];
  red[pg][tid & 31] = s;
  dred[tid] = dpart[(b*256 + tid)*16 + h];
  __syncthreads();
  for (int off = 128; off > 0; off >>= 1){
    if (tid < off) dred[tid] += dred[tid + off];
    __syncthreads();
  }
  if (tid < 32){
    float cs = 0.f;
    #pragma unroll
    for (int g = 0; g < 8; ++g) cs += red[g][tid];
    const int col = ch*32 + tid;
    const float qv = cs / dred[0];
    qavB[b*1024 + col]  = qv;
    wvecB[b*1024 + col] = qv * wb[col & 63];
  }
}

// mergeB: grid 128 (bh), 256 thr -> pav -> WuPT[bh][j][i] = pav[i]*Wu[i][j]
__global__ __launch_bounds__(256)
void k_mergeB(const float* __restrict__ cpart, const float* __restrict__ dpart,
              const float* __restrict__ qavB, const float* __restrict__ Wu,
              uint16_t* __restrict__ WuPT)
{
  __shared__ float red[4][64];
  __shared__ float dred[256];
  __shared__ float pav[64];
  const int bh = blockIdx.x, b = bh >> 4, h = bh & 15;
  const int tid = threadIdx.x;
  const int j = tid & 63, pg = tid >> 6;    // 4 groups x 64 partials
  float s = 0.f;
  #pragma unroll
  for (int p = 0; p < 64; ++p)
    s += cpart[(size_t)(b*256 + pg*64 + p)*1024 + h*64 + j];
  red[pg][j] = s;
  dred[tid] = dpart[(b*256 + tid)*16 + h];
  __syncthreads();
  for (int off = 128; off > 0; off >>= 1){
    if (tid < off) dred[tid] += dred[tid + off];
    __syncthreads();
  }
  if (tid < 64){
    const float cs = red[0][tid] + red[1][tid] + red[2][tid] + red[3][tid];
    pav[tid] = qavB[b*1024 + h*64 + tid] * (cs / dred[0]);
  }
  __syncthreads();
  uint16_t* dst = WuPT + (size_t)bh*4096;
  for (int idx = tid; idx < 4096; idx += 256){
    const int i = idx & 63, jcol = idx >> 6;
    dst[idx] = f2bf(pav[i]*Wu[i*64 + jcol]);
  }
}

// ---------------- newr = v @ WuP + bu + q   (per-head MFMA) ----------------
__global__ __launch_bounds__(256)
void k_newr(const uint16_t* __restrict__ qkv, const uint16_t* __restrict__ WuPT,
            const float* __restrict__ bu, uint16_t* __restrict__ newr)
{
  const int bh = blockIdx.x >> 3, st = blockIdx.x & 7;
  const int b = bh >> 4, h = bh & 15;
  const int tid = threadIdx.x, wave = tid >> 6, lane = tid & 63;
  const int l15 = lane & 15, l4 = lane >> 4;
  const int s0 = st*256 + wave*64;
  const uint16_t* vb = qkv + 2048 + h*64;
  const uint16_t* wt = WuPT + (size_t)bh*4096;

  f32x4 acc[4][4] = {};
  #pragma unroll
  for (int ks = 0; ks < 2; ++ks){
    bf16x8 bfr[4];
    #pragma unroll
    for (int n = 0; n < 4; ++n)
      bfr[n] = *(const bf16x8*)(wt + (n*16 + l15)*64 + ks*32 + l4*8);
    #pragma unroll
    for (int m = 0; m < 4; ++m){
      const int s = s0 + m*16 + l15;
      bf16x8 af = *(const bf16x8*)(vb + (size_t)(b*SS + s)*NQKV + ks*32 + l4*8);
      #pragma unroll
      for (int n = 0; n < 4; ++n)
        acc[m][n] = __builtin_amdgcn_mfma_f32_16x16x32_bf16(af, bfr[n], acc[m][n], 0, 0, 0);
    }
  }
  #pragma unroll
  for (int n = 0; n < 4; ++n){
    const int j = n*16 + l15;
    const float bj = bu[j];
    #pragma unroll
    for (int m = 0; m < 4; ++m){
      #pragma unroll
      for (int r = 0; r < 4; ++r){
        const int s = s0 + m*16 + l4*4 + r;
        const size_t qidx = (size_t)(b*SS + s)*NQKV + h*64 + j;
        const float q = bf2f(qkv[qidx]);
        newr[(size_t)(b*SS + s)*DD + h*64 + j] = f2bf(acc[m][n][r] + bj + q);
      }
    }
  }
}

// ---------------- layernorm (bf16 input h, f32 output) ----------------
__global__ __launch_bounds__(256)
void k_ln(const uint16_t* __restrict__ h16, const float* __restrict__ gamma,
          const float* __restrict__ beta, float* __restrict__ out)
{
  __shared__ float r1[256], r2[256];
  const int row = blockIdx.x, tid = threadIdx.x;
  const ushort4 hv = ((const ushort4*)(h16 + (size_t)row*DD))[tid];
  float v0 = bf2f(hv.x), v1 = bf2f(hv.y), v2 = bf2f(hv.z), v3 = bf2f(hv.w);
  float s  = v0 + v1 + v2 + v3;
  float ss = v0*v0 + v1*v1 + v2*v2 + v3*v3;
  r1[tid] = s; r2[tid] = ss; __syncthreads();
  for (int off = 128; off > 0; off >>= 1){
    if (tid < off){ r1[tid] += r1[tid+off]; r2[tid] += r2[tid+off]; }
    __syncthreads();
  }
  const float mu  = r1[0]*(1.f/1024.f);
  const float var = r2[0]*(1.f/1024.f) - mu*mu;
  const float inv = rsqrtf(var + 1e-6f);
  const float4 g  = ((const float4*)gamma)[tid];
  const float4 be = ((const float4*)beta)[tid];
  float4 o;
  o.x = (v0-mu)*inv*g.x + be.x;
  o.y = (v1-mu)*inv*g.y + be.y;
  o.z = (v2-mu)*inv*g.z + be.z;
  o.w = (v3-mu)*inv*g.w + be.w;
  ((float4*)(out + (size_t)row*DD))[tid] = o;
}

// ---------------- launch ----------------
extern "C" void kernel_launch(void* const* d_in, const int* in_sizes, int n_in,
                              void* d_out, int out_size, void* d_ws, size_t ws_size,
                              hipStream_t stream) {
  const float* x    = (const float*)d_in[0];
  const float* mask = (const float*)d_in[1];
  const float* Wq   = (const float*)d_in[2];
  const float* bq   = (const float*)d_in[3];
  const float* Wk   = (const float*)d_in[4];
  const float* bk   = (const float*)d_in[5];
  const float* Wv   = (const float*)d_in[6];
  const float* bv   = (const float*)d_in[7];
  const float* wa   = (const float*)d_in[8];
  const float* ba   = (const float*)d_in[9];
  const float* wb   = (const float*)d_in[10];
  const float* bb   = (const float*)d_in[11];
  const float* Wu   = (const float*)d_in[12];
  const float* bu   = (const float*)d_in[13];
  const float* Wo   = (const float*)d_in[14];
  const float* bo   = (const float*)d_in[15];
  const float* gamma= (const float*)d_in[16];
  const float* beta = (const float*)d_in[17];
  float* out = (float*)d_out;

  char* ws = (char*)d_ws;
  const size_t MB = 1ull << 20;
  uint16_t* xb    = (uint16_t*)(ws);              // 32 MB [16384][1024] bf16
  uint16_t* Wt    = (uint16_t*)(ws + 32*MB);      // 6 MB  [3072][1024]  bf16
  uint16_t* WoT   = (uint16_t*)(ws + 38*MB);      // 2 MB  [1024][1024]  bf16
  float*    bqkv  = (float*)   (ws + 40*MB);      // 12 KB
  uint16_t* WuPT  = (uint16_t*)(ws + 41*MB);      // 1 MB  [128][64][64] bf16
  uint16_t* qkv   = (uint16_t*)(ws + 42*MB);      // 96 MB [16384][3072] bf16
  uint16_t* newr  = (uint16_t*)(ws + 138*MB);     // 32 MB [16384][1024] bf16
  uint16_t* hbuf16= (uint16_t*)(ws + 42*MB);      // 32 MB, aliases dead qkv
  // pooling partials: alias the newr region (dead until k_newr)
  float* cpart = (float*)(ws + 138*MB);           // 8 MB  [2048][1024] f32
  float* dpart = (float*)(ws + 146*MB);           // 128KB [2048][16]   f32
  float* qavB  = (float*)(ws + 147*MB);           // 32 KB [8][1024]
  float* wvecB = (float*)(ws + 148*MB);           // 32 KB [8][1024]

  k_prep<<<6156, 256, 0, stream>>>(x, Wq, Wk, Wv, Wo, bq, bk, bv, xb, Wt, WoT, bqkv);

  k_gemm256<0,12><<<(MTOT/256)*(NQKV/256), 512, 0, stream>>>(xb, Wt, bqkv, nullptr, qkv);

  k_pool<0><<<2048, 256, 0, stream>>>(qkv, mask, wa, ba, nullptr, cpart, dpart);
  k_mergeA<<<256, 256, 0, stream>>>(cpart, dpart, wb, qavB, wvecB);
  k_pool<1><<<2048, 256, 0, stream>>>(qkv, mask, nullptr, bb, wvecB, cpart, dpart);
  k_mergeB<<<128, 256, 0, stream>>>(cpart, dpart, qavB, Wu, WuPT);

  k_newr<<<BB*HH*8, 256, 0, stream>>>(qkv, WuPT, bu, newr);
  k_gemm256<1,4><<<(MTOT/256)*(DD/256), 512, 0, stream>>>(newr, WoT, bo, xb, hbuf16);
  k_ln<<<MTOT, 256, 0, stream>>>(hbuf16, gamma, beta, out);
}

// Round 8
// 219.443 us; speedup vs baseline: 1.0845x; 1.0845x over previous
//
#include <hip/hip_runtime.h>
#include <cstdint>

// ---------------- problem constants ----------------
#define BB 8
#define SS 2048
#define DD 1024
#define HH 16
#define HDIM 64
#define MTOT (BB*SS)          // 16384
#define NQKV 3072

typedef __attribute__((ext_vector_type(8))) __bf16 bf16x8;
typedef __attribute__((ext_vector_type(4))) float f32x4;

#define AS1(p) ((const __attribute__((address_space(1))) void*)(p))
#define AS3(p) ((__attribute__((address_space(3))) void*)(p))

__device__ __forceinline__ float bf2f(uint16_t u){
  return __uint_as_float(((uint32_t)u) << 16);
}
__device__ __forceinline__ uint16_t f2bf(float f){
  uint32_t u = __float_as_uint(f);
  return (uint16_t)((u + 0x7fffu + ((u >> 16) & 1u)) >> 16);
}

// ---------------- merged prep kernel ----------------
__global__ __launch_bounds__(256)
void k_prep(const float* __restrict__ x,
            const float* __restrict__ Wq, const float* __restrict__ Wk,
            const float* __restrict__ Wv, const float* __restrict__ Wo,
            const float* __restrict__ bq, const float* __restrict__ bk,
            const float* __restrict__ bv,
            uint16_t* __restrict__ xb, uint16_t* __restrict__ Wt,
            uint16_t* __restrict__ WoT, float* __restrict__ bqkv)
{
  __shared__ float t[32][33];
  const int blk = blockIdx.x, tid = threadIdx.x;
  if (blk < 2048){
    const int n4 = MTOT*DD/4;
    for (int i = blk*256 + tid; i < n4; i += 2048*256){
      float4 v = reinterpret_cast<const float4*>(x)[i];
      ushort4 o;
      o.x = f2bf(v.x); o.y = f2bf(v.y); o.z = f2bf(v.z); o.w = f2bf(v.w);
      reinterpret_cast<ushort4*>(xb)[i] = o;
    }
  } else if (blk < 6144){
    const int zb = blk - 2048;
    const int z = zb >> 10, rem = zb & 1023;
    const int by = rem >> 5, bx = rem & 31;
    const float* src = (z==0)?Wq:(z==1)?Wk:(z==2)?Wv:Wo;
    uint16_t* dst = (z<3) ? (Wt + (size_t)z*1024*1024) : WoT;
    const int k0 = by*32, n0 = bx*32;
    const int tx = tid & 31, ty = tid >> 5;
    #pragma unroll
    for (int r = 0; r < 4; ++r)
      t[ty + r*8][tx] = src[(size_t)(k0 + ty + r*8)*1024 + n0 + tx];
    __syncthreads();
    #pragma unroll
    for (int r = 0; r < 4; ++r)
      dst[(size_t)(n0 + ty + r*8)*1024 + k0 + tx] = f2bf(t[tx][ty + r*8]);
  } else {
    const int i = (blk - 6144)*256 + tid;
    if (i < NQKV)
      bqkv[i] = (i < 1024) ? bq[i] : (i < 2048) ? bk[i-1024] : bv[i-2048];
  }
}

// ============ 256x256 8-phase GEMM (R6 schedule) + fused alpha-pool epilogue ============
// EPI 0 (QKV): out bf16 = acc + bias; blocks with n0<1024 additionally compute the
//   alpha-pool partials from registers: per wave (128 rows x 64 cols = 1 head),
//   score = q-row . wa (shfl over l15 group), E = exp(score/8 + mask), accumulate
//   E*q per column (reduce over l4 via shfl 16/32) -> cpartA[rowblk][col], and
//   sum E -> dpartA[rowblk][head]. Shift-free softmax exact (|score| ~ 0.1).
// EPI 1 (Wo):  out bf16 = acc + bias + bf16 resid.
#define BARRIER __builtin_amdgcn_s_barrier()

#define READA(BUF, MH) { \
  const uint16_t* _sl = lds + ((BUF)*4 + (MH))*8192; \
  _Pragma("unroll") \
  for (int f = 0; f < 4; ++f) \
    _Pragma("unroll") \
    for (int ks = 0; ks < 2; ++ks) \
      a[f][ks] = *(const bf16x8*)(_sl + (wm*64 + f*16 + l15)*64 + (((ks*4 + l4) ^ l7)<<3)); \
}

#define READB(BUF, NH, BV) { \
  const uint16_t* _sl = lds + ((BUF)*4 + 2 + (NH))*8192; \
  _Pragma("unroll") \
  for (int j = 0; j < 2; ++j) \
    _Pragma("unroll") \
    for (int ks = 0; ks < 2; ++ks) \
      BV[j][ks] = *(const bf16x8*)(_sl + (wn*32 + j*16 + l15)*64 + (((ks*4 + l4) ^ l7)<<3)); \
}

#define MMA(MH, NH, BV) { \
  __builtin_amdgcn_s_setprio(1); \
  _Pragma("unroll") \
  for (int ks = 0; ks < 2; ++ks) \
    _Pragma("unroll") \
    for (int f = 0; f < 4; ++f) \
      _Pragma("unroll") \
      for (int j = 0; j < 2; ++j) \
        acc[(MH)*4+f][(NH)*2+j] = __builtin_amdgcn_mfma_f32_16x16x32_bf16(a[f][ks], BV[j][ks], acc[(MH)*4+f][(NH)*2+j], 0, 0, 0); \
  __builtin_amdgcn_s_setprio(0); }

#define STAGEA(T, H) { \
  char* _d = (char*)lds + ((((T)&1)*4 + (H))*16384) + wave*1024; \
  _Pragma("unroll") \
  for (int l = 0; l < 2; ++l) \
    __builtin_amdgcn_global_load_lds(AS1(pA + (l*131072 + (H)*65536 + (T)*64)), AS3(_d + l*8192), 16, 0, 0); \
}

#define STAGEB(T, H) { \
  char* _d = (char*)lds + ((((T)&1)*4 + 2 + (H))*16384) + wave*1024; \
  _Pragma("unroll") \
  for (int l = 0; l < 2; ++l) \
    __builtin_amdgcn_global_load_lds(AS1(pB + (l*131072 + (H)*32768 + (T)*64)), AS3(_d + l*8192), 16, 0, 0); \
}

template<int EPI, int NB_T>
__global__ __launch_bounds__(512)
void k_gemm256(const uint16_t* __restrict__ A, const uint16_t* __restrict__ Bt,
               const float* __restrict__ bias, const uint16_t* __restrict__ resid16,
               uint16_t* __restrict__ Cout,
               const float* __restrict__ waP, const float* __restrict__ baP,
               const float* __restrict__ maskP,
               float* __restrict__ cpartA, float* __restrict__ dpartA)
{
  constexpr int N = NB_T * 256;
  __shared__ uint16_t lds[8 * 8192];   // 128 KiB
  const int tid = threadIdx.x;
  const int lane = tid & 63, wave = tid >> 6;
  const int wm = wave >> 2, wn = wave & 3;     // 2 M-waves x 4 N-waves
  const int l15 = lane & 15, l4 = lane >> 4, l7 = lane & 7;

  const int nwg = gridDim.x, cpx = nwg >> 3, bid = blockIdx.x;
  const int wg = (bid & 7) * cpx + (bid >> 3);
  const int m0 = (wg / NB_T) << 8, n0 = (wg % NB_T) << 8;

  const int colbase = (((tid & 7) ^ ((tid >> 3) & 7)) << 3);
  const uint16_t* pA = A  + (size_t)(m0 + (tid >> 3)) * 1024 + colbase;
  const uint16_t* pB = Bt + (size_t)(n0 + ((tid >> 8) << 6) + ((tid >> 3) & 31)) * 1024 + colbase;

  f32x4 acc[8][4] = {};
  bf16x8 a[4][2], b0[2][2], b1[2][2];

  STAGEA(0,0); STAGEB(0,1); STAGEA(0,1); STAGEB(0,0);
  STAGEA(1,0); STAGEB(1,1); STAGEA(1,1);
  asm volatile("s_waitcnt vmcnt(6)" ::: "memory");
  BARRIER;

  #pragma unroll
  for (int I = 0; I < 7; ++I){
    const int e = 2*I;
    READA(0,0); READB(0,0,b0); STAGEB(e+1, 0);
    BARRIER; MMA(0,0,b0); BARRIER;
    READB(0,1,b1); STAGEA(e+2, 0);
    BARRIER; MMA(0,1,b1); BARRIER;
    READA(0,1); STAGEB(e+2, 1);
    BARRIER; MMA(1,1,b1); BARRIER;
    STAGEA(e+2, 1);
    asm volatile("s_waitcnt vmcnt(6)" ::: "memory");
    BARRIER; MMA(1,0,b0); BARRIER;
    READA(1,0); READB(1,0,b0); STAGEB(e+2, 0);
    BARRIER; MMA(0,0,b0); BARRIER;
    READB(1,1,b1); STAGEA(e+3, 0);
    BARRIER; MMA(0,1,b1); BARRIER;
    READA(1,1); STAGEB(e+3, 1);
    BARRIER; MMA(1,1,b1); BARRIER;
    STAGEA(e+3, 1);
    asm volatile("s_waitcnt vmcnt(6)" ::: "memory");
    BARRIER; MMA(1,0,b0); BARRIER;
  }

  {
    READA(0,0); READB(0,0,b0); STAGEB(15, 0);
    BARRIER; MMA(0,0,b0); BARRIER;
    READB(0,1,b1);
    BARRIER; MMA(0,1,b1); BARRIER;
    READA(0,1);
    BARRIER; MMA(1,1,b1); BARRIER;
    asm volatile("s_waitcnt vmcnt(0)" ::: "memory");
    BARRIER; MMA(1,0,b0); BARRIER;
    READA(1,0); READB(1,0,b0);
    BARRIER; MMA(0,0,b0); BARRIER;
    READB(1,1,b1);
    BARRIER; MMA(0,1,b1); BARRIER;
    READA(1,1);
    BARRIER; MMA(1,1,b1); BARRIER;
    MMA(1,0,b0);
  }

  // ---- C-write
  #pragma unroll
  for (int mh = 0; mh < 2; ++mh)
  #pragma unroll
  for (int f = 0; f < 4; ++f)
  #pragma unroll
  for (int nh = 0; nh < 2; ++nh)
  #pragma unroll
  for (int j = 0; j < 2; ++j){
    const int gcol = n0 + wn*64 + nh*32 + j*16 + l15;
    const float bi = bias[gcol];
    const int rbase = m0 + wm*128 + mh*64 + f*16 + l4*4;
    #pragma unroll
    for (int rr = 0; rr < 4; ++rr){
      const size_t idx = (size_t)(rbase + rr)*N + gcol;
      float v = acc[mh*4+f][nh*2+j][rr] + bi;
      if (EPI == 1) v += bf2f(resid16[idx]);
      Cout[idx] = f2bf(v);
    }
  }

  // ---- fused alpha-pool (q columns only) ----
  if (EPI == 0 && n0 < 1024){
    const int hg = (n0 >> 6) + wn;           // global head 0..15
    const float bav = baP[0];
    float bcol[2][2], wv[2][2];
    #pragma unroll
    for (int nh = 0; nh < 2; ++nh)
    #pragma unroll
    for (int j = 0; j < 2; ++j){
      const int c = nh*32 + j*16 + l15;
      bcol[nh][j] = bias[n0 + wn*64 + c];
      wv[nh][j]   = waP[c];
    }
    float colacc[2][2] = {{0.f,0.f},{0.f,0.f}};
    float esum = 0.f;
    #pragma unroll
    for (int mh = 0; mh < 2; ++mh)
    #pragma unroll
    for (int f = 0; f < 4; ++f)
    #pragma unroll
    for (int rr = 0; rr < 4; ++rr){
      float qv[2][2];
      float p = 0.f;
      #pragma unroll
      for (int nh = 0; nh < 2; ++nh)
      #pragma unroll
      for (int j = 0; j < 2; ++j){
        qv[nh][j] = acc[mh*4+f][nh*2+j][rr] + bcol[nh][j];
        p += qv[nh][j] * wv[nh][j];
      }
      p += __shfl_xor(p, 1); p += __shfl_xor(p, 2);
      p += __shfl_xor(p, 4); p += __shfl_xor(p, 8);
      const int grow = m0 + wm*128 + mh*64 + f*16 + l4*4 + rr;
      const float E = __expf((p + bav)*0.125f + maskP[grow]);
      esum += E;
      #pragma unroll
      for (int nh = 0; nh < 2; ++nh)
      #pragma unroll
      for (int j = 0; j < 2; ++j)
        colacc[nh][j] += E * qv[nh][j];
    }
    const int rb = (m0 >> 7) + wm;           // global rowblock 0..127
    #pragma unroll
    for (int nh = 0; nh < 2; ++nh)
    #pragma unroll
    for (int j = 0; j < 2; ++j){
      float v = colacc[nh][j];
      v += __shfl_xor(v, 16); v += __shfl_xor(v, 32);
      if (l4 == 0)
        cpartA[(size_t)rb*1024 + n0 + wn*64 + nh*32 + j*16 + l15] = v;
    }
    esum += __shfl_xor(esum, 16); esum += __shfl_xor(esum, 32);
    if (lane == 0) dpartA[rb*16 + hg] = esum;
  }
}

// ---- mergeA: grid 32 (b x 4 col-chunks), 256 thr -> qavB, wvecB ----
__global__ __launch_bounds__(256)
void k_mergeA(const float* __restrict__ cpartA, const float* __restrict__ dpartA,
              const float* __restrict__ wb,
              float* __restrict__ qavB, float* __restrict__ wvecB)
{
  __shared__ float dsum[16];
  const int blk = blockIdx.x, tid = threadIdx.x;
  const int b = blk >> 2, c = (blk & 3)*256 + tid;
  if (tid < 16){
    float d = 0.f;
    #pragma unroll
    for (int rb = 0; rb < 16; ++rb) d += dpartA[(b*16 + rb)*16 + tid];
    dsum[tid] = d;
  }
  __syncthreads();
  float s = 0.f;
  #pragma unroll
  for (int rb = 0; rb < 16; ++rb) s += cpartA[(size_t)(b*16 + rb)*1024 + c];
  const float qv = s / dsum[(c >> 6) & 15];
  qavB[b*1024 + c]  = qv;
  wvecB[b*1024 + c] = qv * wb[c & 63];
}

// ---- beta pool: grid 512 (32 rows each), 256 thr ----
__global__ __launch_bounds__(256)
void k_poolB(const uint16_t* __restrict__ qkv, const float* __restrict__ mask,
             const float* __restrict__ bbP, const float* __restrict__ wvecB,
             float* __restrict__ cpartB, float* __restrict__ dpartB)
{
  __shared__ float probe[1024];
  const int blk = blockIdx.x, tid = threadIdx.x;
  const int r0 = blk*32, b = r0 >> 11;
  #pragma unroll
  for (int k2 = 0; k2 < 4; ++k2)
    probe[k2*256 + tid] = wvecB[b*1024 + k2*256 + tid];
  __syncthreads();
  const float bias = bbP[0];
  const uint16_t* base = qkv + 1024;
  const int c0 = tid*4;
  const float p0 = probe[c0], p1 = probe[c0+1], p2 = probe[c0+2], p3 = probe[c0+3];
  float a0 = 0.f, a1 = 0.f, a2 = 0.f, a3 = 0.f, dsum = 0.f;
  for (int r = 0; r < 32; ++r){
    const int row = r0 + r;
    const ushort4 raw = *(const ushort4*)(base + (size_t)row*NQKV + c0);
    const float v0 = bf2f(raw.x), v1 = bf2f(raw.y), v2 = bf2f(raw.z), v3 = bf2f(raw.w);
    float s = v0*p0 + v1*p1 + v2*p2 + v3*p3;
    s += __shfl_xor(s, 1); s += __shfl_xor(s, 2);
    s += __shfl_xor(s, 4); s += __shfl_xor(s, 8);
    const float E = __expf((s + bias)*0.125f + mask[row]);
    a0 += v0*E; a1 += v1*E; a2 += v2*E; a3 += v3*E;
    dsum += E;
  }
  float* cp = cpartB + (size_t)blk*1024 + c0;
  cp[0] = a0; cp[1] = a1; cp[2] = a2; cp[3] = a3;
  if ((tid & 15) == 0) dpartB[blk*16 + (tid >> 4)] = dsum;
}

// ---- mergeB: grid 128 (bh), 256 thr -> pav -> WuPT ----
__global__ __launch_bounds__(256)
void k_mergeB(const float* __restrict__ cpartB, const float* __restrict__ dpartB,
              const float* __restrict__ qavB, const float* __restrict__ Wu,
              uint16_t* __restrict__ WuPT)
{
  __shared__ float red[4][64];
  __shared__ float dsh[4];
  __shared__ float pav[64];
  const int bh = blockIdx.x, b = bh >> 4, h = bh & 15;
  const int tid = threadIdx.x, j = tid & 63, pg = tid >> 6;
  float s = 0.f;
  #pragma unroll
  for (int p = 0; p < 16; ++p)
    s += cpartB[(size_t)(b*64 + pg*16 + p)*1024 + h*64 + j];
  red[pg][j] = s;
  if (j == 0){
    float d = 0.f;
    #pragma unroll
    for (int p = 0; p < 16; ++p) d += dpartB[(b*64 + pg*16 + p)*16 + h];
    dsh[pg] = d;
  }
  __syncthreads();
  if (tid < 64){
    const float cs = red[0][tid] + red[1][tid] + red[2][tid] + red[3][tid];
    const float dd = dsh[0] + dsh[1] + dsh[2] + dsh[3];
    pav[tid] = qavB[b*1024 + h*64 + tid] * (cs / dd);
  }
  __syncthreads();
  uint16_t* dst = WuPT + (size_t)bh*4096;
  for (int idx = tid; idx < 4096; idx += 256){
    const int i = idx & 63, jcol = idx >> 6;
    dst[idx] = f2bf(pav[i]*Wu[i*64 + jcol]);
  }
}

// ---------------- newr = v @ WuP + bu + q   (per-head MFMA) ----------------
__global__ __launch_bounds__(256)
void k_newr(const uint16_t* __restrict__ qkv, const uint16_t* __restrict__ WuPT,
            const float* __restrict__ bu, uint16_t* __restrict__ newr)
{
  const int bh = blockIdx.x >> 3, st = blockIdx.x & 7;
  const int b = bh >> 4, h = bh & 15;
  const int tid = threadIdx.x, wave = tid >> 6, lane = tid & 63;
  const int l15 = lane & 15, l4 = lane >> 4;
  const int s0 = st*256 + wave*64;
  const uint16_t* vb = qkv + 2048 + h*64;
  const uint16_t* wt = WuPT + (size_t)bh*4096;

  f32x4 acc[4][4] = {};
  #pragma unroll
  for (int ks = 0; ks < 2; ++ks){
    bf16x8 bfr[4];
    #pragma unroll
    for (int n = 0; n < 4; ++n)
      bfr[n] = *(const bf16x8*)(wt + (n*16 + l15)*64 + ks*32 + l4*8);
    #pragma unroll
    for (int m = 0; m < 4; ++m){
      const int s = s0 + m*16 + l15;
      bf16x8 af = *(const bf16x8*)(vb + (size_t)(b*SS + s)*NQKV + ks*32 + l4*8);
      #pragma unroll
      for (int n = 0; n < 4; ++n)
        acc[m][n] = __builtin_amdgcn_mfma_f32_16x16x32_bf16(af, bfr[n], acc[m][n], 0, 0, 0);
    }
  }
  #pragma unroll
  for (int n = 0; n < 4; ++n){
    const int j = n*16 + l15;
    const float bj = bu[j];
    #pragma unroll
    for (int m = 0; m < 4; ++m){
      #pragma unroll
      for (int r = 0; r < 4; ++r){
        const int s = s0 + m*16 + l4*4 + r;
        const size_t qidx = (size_t)(b*SS + s)*NQKV + h*64 + j;
        const float q = bf2f(qkv[qidx]);
        newr[(size_t)(b*SS + s)*DD + h*64 + j] = f2bf(acc[m][n][r] + bj + q);
      }
    }
  }
}

// ---------------- layernorm (bf16 input h, f32 output) ----------------
__global__ __launch_bounds__(256)
void k_ln(const uint16_t* __restrict__ h16, const float* __restrict__ gamma,
          const float* __restrict__ beta, float* __restrict__ out)
{
  __shared__ float r1[256], r2[256];
  const int row = blockIdx.x, tid = threadIdx.x;
  const ushort4 hv = ((const ushort4*)(h16 + (size_t)row*DD))[tid];
  float v0 = bf2f(hv.x), v1 = bf2f(hv.y), v2 = bf2f(hv.z), v3 = bf2f(hv.w);
  float s  = v0 + v1 + v2 + v3;
  float ss = v0*v0 + v1*v1 + v2*v2 + v3*v3;
  r1[tid] = s; r2[tid] = ss; __syncthreads();
  for (int off = 128; off > 0; off >>= 1){
    if (tid < off){ r1[tid] += r1[tid+off]; r2[tid] += r2[tid+off]; }
    __syncthreads();
  }
  const float mu  = r1[0]*(1.f/1024.f);
  const float var = r2[0]*(1.f/1024.f) - mu*mu;
  const float inv = rsqrtf(var + 1e-6f);
  const float4 g  = ((const float4*)gamma)[tid];
  const float4 be = ((const float4*)beta)[tid];
  float4 o;
  o.x = (v0-mu)*inv*g.x + be.x;
  o.y = (v1-mu)*inv*g.y + be.y;
  o.z = (v2-mu)*inv*g.z + be.z;
  o.w = (v3-mu)*inv*g.w + be.w;
  ((float4*)(out + (size_t)row*DD))[tid] = o;
}

// ---------------- launch ----------------
extern "C" void kernel_launch(void* const* d_in, const int* in_sizes, int n_in,
                              void* d_out, int out_size, void* d_ws, size_t ws_size,
                              hipStream_t stream) {
  const float* x    = (const float*)d_in[0];
  const float* mask = (const float*)d_in[1];
  const float* Wq   = (const float*)d_in[2];
  const float* bq   = (const float*)d_in[3];
  const float* Wk   = (const float*)d_in[4];
  const float* bk   = (const float*)d_in[5];
  const float* Wv   = (const float*)d_in[6];
  const float* bv   = (const float*)d_in[7];
  const float* wa   = (const float*)d_in[8];
  const float* ba   = (const float*)d_in[9];
  const float* wb   = (const float*)d_in[10];
  const float* bb   = (const float*)d_in[11];
  const float* Wu   = (const float*)d_in[12];
  const float* bu   = (const float*)d_in[13];
  const float* Wo   = (const float*)d_in[14];
  const float* bo   = (const float*)d_in[15];
  const float* gamma= (const float*)d_in[16];
  const float* beta = (const float*)d_in[17];
  float* out = (float*)d_out;

  char* ws = (char*)d_ws;
  const size_t MB = 1ull << 20;
  uint16_t* xb    = (uint16_t*)(ws);              // 32 MB [16384][1024] bf16
  uint16_t* Wt    = (uint16_t*)(ws + 32*MB);      // 6 MB  [3072][1024]  bf16
  uint16_t* WoT   = (uint16_t*)(ws + 38*MB);      // 2 MB  [1024][1024]  bf16
  float*    bqkv  = (float*)   (ws + 40*MB);      // 12 KB
  uint16_t* WuPT  = (uint16_t*)(ws + 41*MB);      // 1 MB  [128][64][64] bf16
  uint16_t* qkv   = (uint16_t*)(ws + 42*MB);      // 96 MB [16384][3072] bf16
  uint16_t* newr  = (uint16_t*)(ws + 138*MB);     // 32 MB [16384][1024] bf16
  uint16_t* hbuf16= (uint16_t*)(ws + 42*MB);      // 32 MB, aliases dead qkv
  // pooling partials: alias the newr region (dead until k_newr)
  float* cpartA = (float*)(ws + 138*MB);          // 512KB [128][1024] f32
  float* dpartA = (float*)(ws + 139*MB);          // 8 KB  [128][16]
  float* cpartB = (float*)(ws + 140*MB);          // 2 MB  [512][1024]
  float* dpartB = (float*)(ws + 142*MB);          // 32 KB [512][16]
  float* qavB   = (float*)(ws + 143*MB);          // 32 KB [8][1024]
  float* wvecB  = (float*)(ws + 144*MB);          // 32 KB [8][1024]

  k_prep<<<6156, 256, 0, stream>>>(x, Wq, Wk, Wv, Wo, bq, bk, bv, xb, Wt, WoT, bqkv);

  k_gemm256<0,12><<<(MTOT/256)*(NQKV/256), 512, 0, stream>>>(
      xb, Wt, bqkv, nullptr, qkv, wa, ba, mask, cpartA, dpartA);

  k_mergeA<<<32, 256, 0, stream>>>(cpartA, dpartA, wb, qavB, wvecB);
  k_poolB<<<512, 256, 0, stream>>>(qkv, mask, bb, wvecB, cpartB, dpartB);
  k_mergeB<<<128, 256, 0, stream>>>(cpartB, dpartB, qavB, Wu, WuPT);

  k_newr<<<BB*HH*8, 256, 0, stream>>>(qkv, WuPT, bu, newr);
  k_gemm256<1,4><<<(MTOT/256)*(DD/256), 512, 0, stream>>>(
      newr, WoT, bo, xb, hbuf16, nullptr, nullptr, nullptr, nullptr, nullptr);
  k_ln<<<MTOT, 256, 0, stream>>>(hbuf16, gamma, beta, out);
}